// Round 8
// baseline (395.883 us; speedup 1.0000x reference)
//
#include <hip/hip_runtime.h>

typedef unsigned short u16;
typedef __bf16 bf16x8 __attribute__((ext_vector_type(8)));
typedef float f32x4 __attribute__((ext_vector_type(4)));
typedef u16 u16x8 __attribute__((ext_vector_type(8)));

#define T_TOK 2048
#define HID   1024
#define NEXP  32
#define IM    512
#define SI    2048
#define TOPK  6
#define PLAN_MAX 160

// exact RNE float->bf16
__device__ __forceinline__ u16 f2bf(float f){
  unsigned u = __float_as_uint(f);
  u += 0x7FFFu + ((u >> 16) & 1u);
  return (u16)(u >> 16);
}

// async global->LDS, 16B per lane. LDS dest must be wave-uniform base + lane*16.
__device__ __forceinline__ void gll16(const void* g, void* l){
  __builtin_amdgcn_global_load_lds((const __attribute__((address_space(1))) void*)g,
                                   (__attribute__((address_space(3))) void*)l, 16, 0, 0);
}

__device__ __forceinline__ u16x8 cvt2(float4 a, float4 b){
  u16x8 o;
  o[0] = f2bf(a.x); o[1] = f2bf(a.y); o[2] = f2bf(a.z); o[3] = f2bf(a.w);
  o[4] = f2bf(b.x); o[5] = f2bf(b.y); o[6] = f2bf(b.z); o[7] = f2bf(b.w);
  return o;
}

// K1: router (blocks 0..511) + cvt x -> xb bf16 (512..1535). Weights are NOT
// pre-converted anymore — GEMMs reg-stage fp32 B and convert in-kernel.
__global__ __launch_bounds__(256) void prep1_kernel(
    const float* __restrict__ x, const float* __restrict__ gate,
    const float* __restrict__ ebias, u16x8* __restrict__ xb,
    int* __restrict__ ce, float* __restrict__ cw, int* __restrict__ done){
  int blk = blockIdx.x;
  if (blk == 0 && threadIdx.x == 0) *done = 0;
  if (blk >= 512){
    long i = (long)(blk - 512) * 256 + threadIdx.x;   // < 262144
    const float4* s = (const float4*)x;
    float4 a = s[2*i], b = s[2*i+1];
    xb[i] = cvt2(a, b);
    return;
  }
  // ---- router: 4 tokens/block, 1 wave/token, register cross-lane top-k ----
  int wave = threadIdx.x >> 6;
  int lane = threadIdx.x & 63;
  int t = blk * 4 + wave;
  int e = lane & 31, half = lane >> 5;
  const float4* xv = (const float4*)(x + (size_t)t * HID);
  const float4* gv = (const float4*)(gate + (size_t)e * HID);
  double d0a = 0, d1a = 0, d2a = 0, d3a = 0;
  for (int i = half * 128; i < half * 128 + 128; i++){
    float4 a = xv[i], b = gv[i];
    d0a += (double)a.x * b.x; d1a += (double)a.y * b.y;
    d2a += (double)a.z * b.z; d3a += (double)a.w * b.w;
  }
  double acc = (d0a + d1a) + (d2a + d3a);
  acc += __shfl_xor(acc, 32);
  double score = 1.0 / (1.0 + exp(-acc));
  double sc = score + (double)ebias[e];
  double o1  = __shfl_xor(sc, 1);
  double hi  = fmax(sc, o1), lo = fmin(sc, o1);
  double ohi = __shfl_xor(hi, 2), olo = __shfl_xor(lo, 2);
  double gs  = (hi >= ohi) ? hi + fmax(lo, ohi) : ohi + fmax(olo, hi);
  int g = e >> 2;
  int rank = 0;
#pragma unroll
  for (int j = 0; j < 8; j++){
    double gj = __shfl(gs, j * 4);
    if (gj > gs || (gj == gs && j < g)) rank++;
  }
  double cur = (rank < 4) ? sc : 0.0;
  int sel_e[TOPK]; double sel_w[TOPK]; double wsum = 0.0;
#pragma unroll
  for (int k = 0; k < TOPK; k++){
    double bv = cur; int bi = lane;
#pragma unroll
    for (int m = 32; m >= 1; m >>= 1){
      double ov = __shfl_xor(bv, m); int oi = __shfl_xor(bi, m);
      if (ov > bv || (ov == bv && oi < bi)) { bv = ov; bi = oi; }
    }
    if ((bi & 31) == e) cur = -1e300;
    double ws = __shfl(score, bi);
    sel_e[k] = bi; sel_w[k] = ws; wsum += ws;
  }
  double scale = 2.5 / (wsum + 1e-20);
#pragma unroll
  for (int k = 0; k < TOPK; k++){
    if (lane == k){                       // compile-time idx -> no scratch spill
      ce[t * TOPK + k] = sel_e[k] & 31;
      cw[t * TOPK + k] = (float)(sel_w[k] * scale);
    }
  }
}

// 32 blocks (one per expert): ordered compaction via ballot prefix scan.
// Last-arriving block builds the dense tile plan.
__global__ __launch_bounds__(256) void build_plan_kernel(const int* __restrict__ ce,
                                                         const float* __restrict__ cw,
                                                         int* __restrict__ cnt,
                                                         int* __restrict__ tok,
                                                         float* __restrict__ wl,
                                                         int* __restrict__ done,
                                                         int* __restrict__ plan){
  int e = blockIdx.x;
  int tid = threadIdx.x, lane = tid & 63, wave = tid >> 6;
  __shared__ int wsum[4];
  __shared__ int lastflag;
  int running = 0;
  for (int base = 0; base < T_TOK * TOPK; base += 256){
    int i = base + tid;                       // 12288 = 48*256, no bounds check
    bool m = (ce[i] == e);
    unsigned long long bal = __ballot(m);
    int woff = __popcll(bal & ((1ull << lane) - 1ull));
    if (lane == 0) wsum[wave] = __popcll(bal);
    __syncthreads();
    int wbase = 0;
#pragma unroll
    for (int wv = 0; wv < 4; wv++) if (wv < wave) wbase += wsum[wv];
    int btot = wsum[0] + wsum[1] + wsum[2] + wsum[3];
    if (m){
      int t = i / TOPK, k = i - t * TOPK;
      int pos = running + wbase + woff;
      tok[e * T_TOK + pos] = (t << 3) | k;
      wl[e * T_TOK + pos] = cw[i];
    }
    running += btot;
    __syncthreads();                          // wsum WAR hazard for next iter
  }
  if (tid == 0){
    atomicExch(&cnt[e], running);             // write-through, device-visible
    __threadfence();
    lastflag = (atomicAdd(done, 1) == NEXP - 1);
  }
  __syncthreads();
  if (lastflag){
    __threadfence();                          // acquire: other blocks' cnt visible
    if (tid < PLAN_MAX) plan[1 + tid] = -1;
    __syncthreads();
    if (tid == 0){
      int n = 0;
      for (int ee = 0; ee < NEXP; ee++){
        int c = (ee == e) ? running : cnt[ee];
        for (int tb = 0; tb < c; tb += 128) plan[1 + n++] = (tb << 8) | ee;
      }
      plan[0] = n;
    }
  }
}

// ---- 128x128 tile, BK=32, 3-LDS-buffer counted-vmcnt pipeline (round-5 core)
// with the B operand REG-STAGED from fp32 (T14): 4 global_load_dwordx4 fp32 ->
// cvt2 -> 2 ds_write_b128, producing the exact bf16 LDS image gll16 of a
// pre-converted copy would give (source-seg swizzle x2 on byte offsets).
// Stage = 2 gll16 (A bf16) + 4 dwordx4 (B fp32) = 6 vmcnt ops; steady-state
// vmcnt(6) keeps one full stage in flight across the barriers. B regs ping-pong
// between two statically-named float4 sets (rule #20) via 2x-unrolled loop.
// iters must be even and >= 4 (16/32/64 here).
__device__ __forceinline__ void gemm_pipe(
    const char* gA0, const char* gA1, const char* gB0f, const char* gB1f,
    u16* lA, u16* lB, int iters, int tid, int wrow, int wcol, int qsw, int l16,
    f32x4 acc[4][4])
{
  char* bA  = (char*)lA + tid*16;
  char* bBw = (char*)lB + tid*16;
  float4 p0a, p0b, p0c, p0d, p1a, p1b, p1c, p1d;
#define ASTAGE(t, b) do { \
    gll16(gA0 + (size_t)(t)*64, bA + (size_t)(b)*8192); \
    gll16(gA1 + (size_t)(t)*64, bA + (size_t)(b)*8192 + 4096); } while(0)
#define BLOAD(t, Pa, Pb, Pc, Pd) do { \
    Pa = *(const float4*)(gB0f + (size_t)(t)*128); \
    Pb = *(const float4*)(gB0f + (size_t)(t)*128 + 16); \
    Pc = *(const float4*)(gB1f + (size_t)(t)*128); \
    Pd = *(const float4*)(gB1f + (size_t)(t)*128 + 16); } while(0)
#define BWRITE(Pa, Pb, Pc, Pd, b) do { \
    *(u16x8*)(bBw + (size_t)(b)*8192)        = cvt2(Pa, Pb); \
    *(u16x8*)(bBw + (size_t)(b)*8192 + 4096) = cvt2(Pc, Pd); } while(0)
#define COMPUTE(rbuf) do { \
    const u16* rA = lA + (rbuf)*4096; \
    const u16* rB = lB + (rbuf)*4096; \
    bf16x8 af[4], bfr[4]; \
    _Pragma("unroll") \
    for (int mt = 0; mt < 4; mt++) af[mt]  = *(const bf16x8*)&rA[(wrow + mt*16 + l16)*32 + qsw*8]; \
    _Pragma("unroll") \
    for (int nt = 0; nt < 4; nt++) bfr[nt] = *(const bf16x8*)&rB[(wcol + nt*16 + l16)*32 + qsw*8]; \
    _Pragma("unroll") \
    for (int mt = 0; mt < 4; mt++) \
    _Pragma("unroll") \
      for (int nt = 0; nt < 4; nt++) \
        acc[mt][nt] = __builtin_amdgcn_mfma_f32_16x16x32_bf16(af[mt], bfr[nt], acc[mt][nt], 0, 0, 0); \
    } while(0)

  // prologue: tiles 0,1 in flight; tile0's B written to LDS once landed
  ASTAGE(0, 0); BLOAD(0, p0a, p0b, p0c, p0d);
  ASTAGE(1, 1); BLOAD(1, p1a, p1b, p1c, p1d);
  asm volatile("s_waitcnt vmcnt(6)" ::: "memory");     // stage0 landed
  BWRITE(p0a, p0b, p0c, p0d, 0);
  int rb = 0;
  for (int t = 0; t <= iters - 4; t += 2){
    // even body: issue t+2 -> set0; write t+1 (set1)
    {
      int b2 = rb + 2; if (b2 >= 3) b2 -= 3;
      ASTAGE(t + 2, b2); BLOAD(t + 2, p0a, p0b, p0c, p0d);
      asm volatile("s_waitcnt vmcnt(6)" ::: "memory"); // stage t+1 landed
      int b1 = rb + 1; if (b1 >= 3) b1 -= 3;
      BWRITE(p1a, p1b, p1c, p1d, b1);
      asm volatile("s_waitcnt lgkmcnt(0)" ::: "memory");
      __builtin_amdgcn_s_barrier();
      asm volatile("" ::: "memory");
      COMPUTE(rb);
      asm volatile("" ::: "memory");
      __builtin_amdgcn_s_barrier();
      asm volatile("" ::: "memory");
      rb = b1;
    }
    // odd body: issue t+3 -> set1; write t+2 (set0)
    {
      int b2 = rb + 2; if (b2 >= 3) b2 -= 3;
      ASTAGE(t + 3, b2); BLOAD(t + 3, p1a, p1b, p1c, p1d);
      asm volatile("s_waitcnt vmcnt(6)" ::: "memory"); // stage t+2 landed
      int b1 = rb + 1; if (b1 >= 3) b1 -= 3;
      BWRITE(p0a, p0b, p0c, p0d, b1);
      asm volatile("s_waitcnt lgkmcnt(0)" ::: "memory");
      __builtin_amdgcn_s_barrier();
      asm volatile("" ::: "memory");
      COMPUTE(rb);
      asm volatile("" ::: "memory");
      __builtin_amdgcn_s_barrier();
      asm volatile("" ::: "memory");
      rb = b1;
    }
  }
  // tail: stage iters-1 still in flight (set1, since iters even)
  asm volatile("s_waitcnt vmcnt(0)" ::: "memory");
  {
    int b1 = rb + 1; if (b1 >= 3) b1 -= 3;
    BWRITE(p1a, p1b, p1c, p1d, b1);
    asm volatile("s_waitcnt lgkmcnt(0)" ::: "memory");
    __builtin_amdgcn_s_barrier();
    asm volatile("" ::: "memory");
    COMPUTE(rb);                                        // tile iters-2
    asm volatile("" ::: "memory");
    __builtin_amdgcn_s_barrier();
    asm volatile("" ::: "memory");
    rb = b1;
  }
  COMPUTE(rb);                                          // tile iters-1
#undef ASTAGE
#undef BLOAD
#undef BWRITE
#undef COMPUTE
}

#define ACC_INIT f32x4 acc[4][4]; \
  _Pragma("unroll") for (int i_ = 0; i_ < 4; i_++) \
  _Pragma("unroll") for (int j_ = 0; j_ < 4; j_++) acc[i_][j_] = (f32x4){0.f,0.f,0.f,0.f};

#define GEO_INIT int tid = threadIdx.x; \
  int lane = tid & 63, wave = tid >> 6, quad = lane >> 4, l16 = lane & 15; \
  int wrow = (wave >> 1)*64, wcol = (wave & 1)*64; \
  int srow = tid >> 2; \
  int sseg = ((tid & 3) ^ ((tid >> 3) & 3)) * 16; \
  int qsw  = quad ^ ((l16 >> 1) & 3);

// K3: blocks [0,256) shared-up, [256,896) expert-up. B = fp32 weights direct.
__global__ __launch_bounds__(256) void up_fused_kernel(
    const u16* __restrict__ xb, const float* __restrict__ supw, const float* __restrict__ upw,
    const int* __restrict__ cnt, const int* __restrict__ tok, const float* __restrict__ wl,
    const int* __restrict__ plan, u16* __restrict__ shh, u16* __restrict__ hws){
  __shared__ u16 lA[3*4096], lB[3*4096];
  GEO_INIT;
  int blk = blockIdx.x;
  if (blk < 256){
    // shared up: shh[2048][2048] = bf16(relu2(X . supW^T))
    int bm = (blk >> 4) * 128, bn = (blk & 15) * 128;
    const char* gA0 = (const char*)(xb + (size_t)(bm + srow)*HID) + sseg;
    const char* gA1 = (const char*)(xb + (size_t)(bm + 64 + srow)*HID) + sseg;
    const char* gB0 = (const char*)supw + (size_t)(bn + srow)*HID*4 + sseg*2;
    const char* gB1 = (const char*)supw + (size_t)(bn + 64 + srow)*HID*4 + sseg*2;
    ACC_INIT;
    gemm_pipe(gA0, gA1, gB0, gB1, lA, lB, HID/32, tid, wrow, wcol, qsw, l16, acc);
#pragma unroll
    for (int mt = 0; mt < 4; mt++)
#pragma unroll
      for (int nt = 0; nt < 4; nt++)
#pragma unroll
        for (int r = 0; r < 4; r++){
          int m = bm + wrow + mt*16 + quad*4 + r;
          int n = bn + wcol + nt*16 + l16;
          float v = acc[mt][nt][r]; v = fmaxf(v, 0.f); v *= v;
          shh[(size_t)m*SI + n] = f2bf(v);
        }
  } else {
    // expert up: hws[slot][512] = bf16(relu2(x_t . up_e^T) * w)
    int eu = blk - 256;
    int pv = plan[1 + (eu >> 2)];
    if (pv < 0) return;
    int e = pv & 255;
    int tb = pv >> 8;
    int c = cnt[e];
    int bn = (eu & 3) * 128;
    const int* tl = tok + e * T_TOK;
    const float* wle = wl + e * T_TOK;
    int s0 = tb + srow;      if (s0 > c-1) s0 = c-1;
    int s1 = tb + 64 + srow; if (s1 > c-1) s1 = c-1;
    int t0 = tl[s0] >> 3, t1 = tl[s1] >> 3;
    const char* gA0 = (const char*)(xb + (size_t)t0*HID) + sseg;
    const char* gA1 = (const char*)(xb + (size_t)t1*HID) + sseg;
    const float* Bb = upw + (size_t)e * IM * HID;
    const char* gB0 = (const char*)Bb + (size_t)(bn + srow)*HID*4 + sseg*2;
    const char* gB1 = (const char*)Bb + (size_t)(bn + 64 + srow)*HID*4 + sseg*2;
    ACC_INIT;
    gemm_pipe(gA0, gA1, gB0, gB1, lA, lB, HID/32, tid, wrow, wcol, qsw, l16, acc);
#pragma unroll
    for (int mt = 0; mt < 4; mt++)
#pragma unroll
      for (int r = 0; r < 4; r++){
        int s = tb + wrow + mt*16 + quad*4 + r;
        if (s < c){
          int code = tl[s];
          float w = wle[s];
          size_t hb = ((size_t)(code >> 3) * TOPK + (code & 7)) * IM;
#pragma unroll
          for (int nt = 0; nt < 4; nt++){
            float v = acc[mt][nt][r]; v = fmaxf(v, 0.f); v = v * v * w;
            hws[hb + bn + wcol + nt*16 + l16] = f2bf(v);
          }
        }
      }
  }
}

// K4: blocks [0,128) shared-down (64 K-iters, dispatched first),
// [128,1408) expert-down (16 K-iters). B = fp32 weights direct.
// out pre-zeroed; all writers atomic.
__global__ __launch_bounds__(256) void down_fused_kernel(
    const u16* __restrict__ shh, const float* __restrict__ sdnw,
    const u16* __restrict__ hws, const float* __restrict__ dnw,
    const int* __restrict__ cnt, const int* __restrict__ tok, const int* __restrict__ plan,
    float* __restrict__ out){
  __shared__ u16 lA[3*4096], lB[3*4096];
  GEO_INIT;
  int blk = blockIdx.x;
  if (blk < 128){
    // shared down: out += H[2048][2048] . sdnW[1024][2048]^T
    int bm = (blk >> 3)*128, bn = (blk & 7)*128;
    const char* gA0 = (const char*)(shh + (size_t)(bm + srow)*SI) + sseg;
    const char* gA1 = (const char*)(shh + (size_t)(bm + 64 + srow)*SI) + sseg;
    const char* gB0 = (const char*)sdnw + (size_t)(bn + srow)*SI*4 + sseg*2;
    const char* gB1 = (const char*)sdnw + (size_t)(bn + 64 + srow)*SI*4 + sseg*2;
    ACC_INIT;
    gemm_pipe(gA0, gA1, gB0, gB1, lA, lB, SI/32, tid, wrow, wcol, qsw, l16, acc);
#pragma unroll
    for (int mt = 0; mt < 4; mt++)
#pragma unroll
      for (int nt = 0; nt < 4; nt++)
#pragma unroll
        for (int r = 0; r < 4; r++){
          int m = bm + wrow + mt*16 + quad*4 + r;
          int n = bn + wcol + nt*16 + l16;
          unsafeAtomicAdd(&out[(size_t)m*HID + n], acc[mt][nt][r]);
        }
  } else {
    // expert down: out[t] += h_slot . down_e^T
    int eu = blk - 128;
    int pv = plan[1 + (eu >> 3)];
    if (pv < 0) return;
    int e = pv & 255;
    int tb = pv >> 8;
    int c = cnt[e];
    int bn = (eu & 7) * 128;
    const int* tl = tok + e * T_TOK;
    int s0 = tb + srow;      if (s0 > c-1) s0 = c-1;
    int s1 = tb + 64 + srow; if (s1 > c-1) s1 = c-1;
    int c0 = tl[s0], c1 = tl[s1];
    const char* gA0 = (const char*)(hws + ((size_t)(c0 >> 3)*TOPK + (c0 & 7))*IM) + sseg;
    const char* gA1 = (const char*)(hws + ((size_t)(c1 >> 3)*TOPK + (c1 & 7))*IM) + sseg;
    const float* Bb = dnw + (size_t)e * HID * IM;
    const char* gB0 = (const char*)Bb + (size_t)(bn + srow)*IM*4 + sseg*2;
    const char* gB1 = (const char*)Bb + (size_t)(bn + 64 + srow)*IM*4 + sseg*2;
    ACC_INIT;
    gemm_pipe(gA0, gA1, gB0, gB1, lA, lB, IM/32, tid, wrow, wcol, qsw, l16, acc);
#pragma unroll
    for (int mt = 0; mt < 4; mt++)
#pragma unroll
      for (int r = 0; r < 4; r++){
        int s = tb + wrow + mt*16 + quad*4 + r;
        if (s < c){
          int code = tl[s];
          float* ob = out + (size_t)(code >> 3) * HID;
#pragma unroll
          for (int nt = 0; nt < 4; nt++)
            unsafeAtomicAdd(&ob[bn + wcol + nt*16 + l16], acc[mt][nt][r]);
        }
      }
  }
}

extern "C" void kernel_launch(void* const* d_in, const int* in_sizes, int n_in,
                              void* d_out, int out_size, void* d_ws, size_t ws_size,
                              hipStream_t stream) {
  const float* x    = (const float*)d_in[0];
  const float* gate = (const float*)d_in[1];
  const float* eb   = (const float*)d_in[2];
  const float* upw  = (const float*)d_in[3];
  const float* dnw  = (const float*)d_in[4];
  const float* supw = (const float*)d_in[5];
  const float* sdnw = (const float*)d_in[6];
  float* out = (float*)d_out;

  char* w = (char*)d_ws;
  size_t o = 0;
  int*   cnt  = (int*)(w + o);   o += 1024;
  int*   plan = (int*)(w + o);   o += 1024;
  int*   ce   = (int*)(w + o);   o += (size_t)T_TOK * TOPK * 4;
  float* cw   = (float*)(w + o); o += (size_t)T_TOK * TOPK * 4;
  int*   tok  = (int*)(w + o);   o += (size_t)NEXP * T_TOK * 4;
  float* wl   = (float*)(w + o); o += (size_t)NEXP * T_TOK * 4;
  u16*   xb   = (u16*)(w + o);   o += (size_t)T_TOK * HID * 2;
  u16*   hws  = (u16*)(w + o);   o += (size_t)T_TOK * TOPK * IM * 2;
  u16*   shh  = (u16*)(w + o);   o += (size_t)T_TOK * SI * 2;
  int*   done = cnt + 32;        // lives in cnt's padding

  (void)hipMemsetAsync(out, 0, (size_t)T_TOK * HID * 4, stream);
  prep1_kernel<<<1536, 256, 0, stream>>>(x, gate, eb, (u16x8*)xb, ce, cw, done);
  build_plan_kernel<<<NEXP, 256, 0, stream>>>(ce, cw, cnt, tok, wl, done, plan);
  up_fused_kernel<<<896, 256, 0, stream>>>(xb, supw, upw, cnt, tok, wl, plan, shh, hws);
  down_fused_kernel<<<1408, 256, 0, stream>>>(shh, sdnw, hws, dnw, cnt, tok, plan, out);
}

// Round 9
// 389.216 us; speedup vs baseline: 1.0171x; 1.0171x over previous
//
#include <hip/hip_runtime.h>

typedef unsigned short u16;
typedef __bf16 bf16x8 __attribute__((ext_vector_type(8)));
typedef float f32x4 __attribute__((ext_vector_type(4)));
typedef u16 u16x8 __attribute__((ext_vector_type(8)));

#define T_TOK 2048
#define HID   1024
#define NEXP  32
#define IM    512
#define SI    2048
#define TOPK  6
#define PLAN_MAX 160

// exact RNE float->bf16
__device__ __forceinline__ u16 f2bf(float f){
  unsigned u = __float_as_uint(f);
  u += 0x7FFFu + ((u >> 16) & 1u);
  return (u16)(u >> 16);
}

// async global->LDS, 16B per lane. LDS dest must be wave-uniform base + lane*16.
__device__ __forceinline__ void gll16(const void* g, void* l){
  __builtin_amdgcn_global_load_lds((const __attribute__((address_space(1))) void*)g,
                                   (__attribute__((address_space(3))) void*)l, 16, 0, 0);
}

__device__ __forceinline__ f32x4 ntld(const f32x4* p){
  return __builtin_nontemporal_load(p);    // read-once fp32: don't pollute LLC
}

__device__ __forceinline__ u16x8 cvt2(f32x4 a, f32x4 b){
  u16x8 o;
  o[0] = f2bf(a[0]); o[1] = f2bf(a[1]); o[2] = f2bf(a[2]); o[3] = f2bf(a[3]);
  o[4] = f2bf(b[0]); o[5] = f2bf(b[1]); o[6] = f2bf(b[2]); o[7] = f2bf(b[3]);
  return o;
}

// K1: router (blocks 0..511) + cvt of ALL fp32->bf16 regions (512..10239).
// Each cvt thread: 4 independent nt 16B loads -> 2x 16B stores (64B/32B per
// thread, 2x the MLP of the round-5 version).
__global__ __launch_bounds__(256) void prep_kernel(
    const float* __restrict__ x, const float* __restrict__ upw, const float* __restrict__ dnw,
    const float* __restrict__ supw, const float* __restrict__ sdnw,
    const float* __restrict__ gate, const float* __restrict__ ebias,
    u16x8* __restrict__ xb, u16x8* __restrict__ upb, u16x8* __restrict__ dnb,
    u16x8* __restrict__ supb, u16x8* __restrict__ sdnb,
    int* __restrict__ ce, float* __restrict__ cw, int* __restrict__ done){
  int blk = blockIdx.x;
  if (blk == 0 && threadIdx.x == 0) *done = 0;
  if (blk >= 512){
    // thread slot i: 2 u16x8 outputs. region slot counts: x 131072, upw 1048576,
    // dnw 1048576, supw 131072, sdnw 131072 (total 2490368 = 9728 blocks)
    long i = (long)(blk - 512) * 256 + threadIdx.x;
    const f32x4* s; u16x8* d;
    if      (i <  131072L){ s = (const f32x4*)x;    d = xb;   }
    else if (i < 1179648L){ s = (const f32x4*)upw;  d = upb;  i -=  131072L; }
    else if (i < 2228224L){ s = (const f32x4*)dnw;  d = dnb;  i -= 1179648L; }
    else if (i < 2359296L){ s = (const f32x4*)supw; d = supb; i -= 2228224L; }
    else                  { s = (const f32x4*)sdnw; d = sdnb; i -= 2359296L; }
    f32x4 a0 = ntld(s + 4*i), a1 = ntld(s + 4*i + 1);
    f32x4 a2 = ntld(s + 4*i + 2), a3 = ntld(s + 4*i + 3);
    d[2*i]     = cvt2(a0, a1);
    d[2*i + 1] = cvt2(a2, a3);
    return;
  }
  // ---- router: 4 tokens/block, 1 wave/token, register cross-lane top-k ----
  int wave = threadIdx.x >> 6;
  int lane = threadIdx.x & 63;
  int t = blk * 4 + wave;
  int e = lane & 31, half = lane >> 5;
  const float4* xv = (const float4*)(x + (size_t)t * HID);
  const float4* gv = (const float4*)(gate + (size_t)e * HID);
  double d0a = 0, d1a = 0, d2a = 0, d3a = 0;
  for (int i = half * 128; i < half * 128 + 128; i++){
    float4 a = xv[i], b = gv[i];
    d0a += (double)a.x * b.x; d1a += (double)a.y * b.y;
    d2a += (double)a.z * b.z; d3a += (double)a.w * b.w;
  }
  double acc = (d0a + d1a) + (d2a + d3a);
  acc += __shfl_xor(acc, 32);
  double score = 1.0 / (1.0 + exp(-acc));
  double sc = score + (double)ebias[e];
  double o1  = __shfl_xor(sc, 1);
  double hi  = fmax(sc, o1), lo = fmin(sc, o1);
  double ohi = __shfl_xor(hi, 2), olo = __shfl_xor(lo, 2);
  double gs  = (hi >= ohi) ? hi + fmax(lo, ohi) : ohi + fmax(olo, hi);
  int g = e >> 2;
  int rank = 0;
#pragma unroll
  for (int j = 0; j < 8; j++){
    double gj = __shfl(gs, j * 4);
    if (gj > gs || (gj == gs && j < g)) rank++;
  }
  double cur = (rank < 4) ? sc : 0.0;
  int sel_e[TOPK]; double sel_w[TOPK]; double wsum = 0.0;
#pragma unroll
  for (int k = 0; k < TOPK; k++){
    double bv = cur; int bi = lane;
#pragma unroll
    for (int m = 32; m >= 1; m >>= 1){
      double ov = __shfl_xor(bv, m); int oi = __shfl_xor(bi, m);
      if (ov > bv || (ov == bv && oi < bi)) { bv = ov; bi = oi; }
    }
    if ((bi & 31) == e) cur = -1e300;
    double ws = __shfl(score, bi);
    sel_e[k] = bi; sel_w[k] = ws; wsum += ws;
  }
  double scale = 2.5 / (wsum + 1e-20);
#pragma unroll
  for (int k = 0; k < TOPK; k++){
    if (lane == k){                       // compile-time idx -> no scratch spill
      ce[t * TOPK + k] = sel_e[k] & 31;
      cw[t * TOPK + k] = (float)(sel_w[k] * scale);
    }
  }
}

// 32 blocks (one per expert): ordered compaction via ballot prefix scan.
// Last-arriving block builds the dense tile plan.
__global__ __launch_bounds__(256) void build_plan_kernel(const int* __restrict__ ce,
                                                         const float* __restrict__ cw,
                                                         int* __restrict__ cnt,
                                                         int* __restrict__ tok,
                                                         float* __restrict__ wl,
                                                         int* __restrict__ done,
                                                         int* __restrict__ plan){
  int e = blockIdx.x;
  int tid = threadIdx.x, lane = tid & 63, wave = tid >> 6;
  __shared__ int wsum[4];
  __shared__ int lastflag;
  int running = 0;
  for (int base = 0; base < T_TOK * TOPK; base += 256){
    int i = base + tid;                       // 12288 = 48*256, no bounds check
    bool m = (ce[i] == e);
    unsigned long long bal = __ballot(m);
    int woff = __popcll(bal & ((1ull << lane) - 1ull));
    if (lane == 0) wsum[wave] = __popcll(bal);
    __syncthreads();
    int wbase = 0;
#pragma unroll
    for (int wv = 0; wv < 4; wv++) if (wv < wave) wbase += wsum[wv];
    int btot = wsum[0] + wsum[1] + wsum[2] + wsum[3];
    if (m){
      int t = i / TOPK, k = i - t * TOPK;
      int pos = running + wbase + woff;
      tok[e * T_TOK + pos] = (t << 3) | k;
      wl[e * T_TOK + pos] = cw[i];
    }
    running += btot;
    __syncthreads();                          // wsum WAR hazard for next iter
  }
  if (tid == 0){
    atomicExch(&cnt[e], running);             // write-through, device-visible
    __threadfence();
    lastflag = (atomicAdd(done, 1) == NEXP - 1);
  }
  __syncthreads();
  if (lastflag){
    __threadfence();                          // acquire: other blocks' cnt visible
    if (tid < PLAN_MAX) plan[1 + tid] = -1;
    __syncthreads();
    if (tid == 0){
      int n = 0;
      for (int ee = 0; ee < NEXP; ee++){
        int c = (ee == e) ? running : cnt[ee];
        for (int tb = 0; tb < c; tb += 128) plan[1 + n++] = (tb << 8) | ee;
      }
      plan[0] = n;
    }
  }
}

// ---- 128x128 tile, BK=32, 3-buffer pipeline with COUNTED vmcnt (round-5 core,
// verified 335.7us): loads for the next 2 K-tiles stay in flight ACROSS the
// barriers (never drain to 0 in the main loop) -> ~2-iter latency tolerance.
// Source 16B-segment swizzle keeps ds_read_b128 conflict-free while the gll16
// LDS dest stays linear (rule #21).
__device__ __forceinline__ void gemm_pipe(
    const char* gA0, const char* gA1, const char* gB0, const char* gB1,
    u16* lA, u16* lB, int iters, int tid, int wrow, int wcol, int qsw, int l16,
    f32x4 acc[4][4])
{
  char* bA = (char*)lA + tid*16;
  char* bB = (char*)lB + tid*16;
#define STAGE(t, b) do { \
    gll16(gA0 + (size_t)(t)*64, bA + (size_t)(b)*8192); \
    gll16(gA1 + (size_t)(t)*64, bA + (size_t)(b)*8192 + 4096); \
    gll16(gB0 + (size_t)(t)*64, bB + (size_t)(b)*8192); \
    gll16(gB1 + (size_t)(t)*64, bB + (size_t)(b)*8192 + 4096); } while(0)
#define COMPUTE(rbuf) do { \
    const u16* rA = lA + (rbuf)*4096; \
    const u16* rB = lB + (rbuf)*4096; \
    bf16x8 af[4], bfr[4]; \
    _Pragma("unroll") \
    for (int mt = 0; mt < 4; mt++) af[mt]  = *(const bf16x8*)&rA[(wrow + mt*16 + l16)*32 + qsw*8]; \
    _Pragma("unroll") \
    for (int nt = 0; nt < 4; nt++) bfr[nt] = *(const bf16x8*)&rB[(wcol + nt*16 + l16)*32 + qsw*8]; \
    _Pragma("unroll") \
    for (int mt = 0; mt < 4; mt++) \
    _Pragma("unroll") \
      for (int nt = 0; nt < 4; nt++) \
        acc[mt][nt] = __builtin_amdgcn_mfma_f32_16x16x32_bf16(af[mt], bfr[nt], acc[mt][nt], 0, 0, 0); \
    } while(0)

  STAGE(0, 0); STAGE(1, 1);
  int rb = 0, sb = 2;
  for (int it = 0; it < iters - 2; ++it){
    STAGE(it + 2, sb);
    asm volatile("s_waitcnt vmcnt(8)" ::: "memory");   // own T(it) landed; T(it+1),T(it+2) in flight
    __builtin_amdgcn_s_barrier();                      // all waves' T(it) landed
    asm volatile("" ::: "memory");
    COMPUTE(rb);
    asm volatile("" ::: "memory");
    __builtin_amdgcn_s_barrier();                      // reads of buf rb done -> may be restaged
    asm volatile("" ::: "memory");
    rb = (rb + 1 == 3) ? 0 : rb + 1;
    sb = (sb + 1 == 3) ? 0 : sb + 1;
  }
  asm volatile("s_waitcnt vmcnt(4)" ::: "memory");
  __builtin_amdgcn_s_barrier();
  asm volatile("" ::: "memory");
  COMPUTE(rb);
  asm volatile("" ::: "memory");
  __builtin_amdgcn_s_barrier();
  asm volatile("" ::: "memory");
  rb = (rb + 1 == 3) ? 0 : rb + 1;
  asm volatile("s_waitcnt vmcnt(0)" ::: "memory");
  __builtin_amdgcn_s_barrier();
  asm volatile("" ::: "memory");
  COMPUTE(rb);
#undef STAGE
#undef COMPUTE
}

#define ACC_INIT f32x4 acc[4][4]; \
  _Pragma("unroll") for (int i_ = 0; i_ < 4; i_++) \
  _Pragma("unroll") for (int j_ = 0; j_ < 4; j_++) acc[i_][j_] = (f32x4){0.f,0.f,0.f,0.f};

#define GEO_INIT int tid = threadIdx.x; \
  int lane = tid & 63, wave = tid >> 6, quad = lane >> 4, l16 = lane & 15; \
  int wrow = (wave >> 1)*64, wcol = (wave & 1)*64; \
  int srow = tid >> 2; \
  int sseg = ((tid & 3) ^ ((tid >> 3) & 3)) * 16; \
  int qsw  = quad ^ ((l16 >> 1) & 3);

// K3: logical blocks [0,256) shared-up, [256,896) expert-up.
// XCD swizzle (T1, bijective: 896 = 8*112): logical l = (h%112)*8 + h/112 puts
// 8 consecutive logicals (which share an A-panel) on ONE XCD's L2.
__global__ __launch_bounds__(256) void up_fused_kernel(
    const u16* __restrict__ xb, const u16* __restrict__ supb, const u16* __restrict__ upb,
    const int* __restrict__ cnt, const int* __restrict__ tok, const float* __restrict__ wl,
    const int* __restrict__ plan, u16* __restrict__ shh, u16* __restrict__ hws){
  __shared__ u16 lA[3*4096], lB[3*4096];
  GEO_INIT;
  int h = blockIdx.x;
  int blk = (h % 112) * 8 + h / 112;
  if (blk < 256){
    // shared up: shh[2048][2048] = bf16(relu2(X . supW^T))
    int bm = (blk >> 4) * 128, bn = (blk & 15) * 128;
    const char* gA0 = (const char*)(xb + (size_t)(bm + srow)*HID) + sseg;
    const char* gA1 = (const char*)(xb + (size_t)(bm + 64 + srow)*HID) + sseg;
    const char* gB0 = (const char*)(supb + (size_t)(bn + srow)*HID) + sseg;
    const char* gB1 = (const char*)(supb + (size_t)(bn + 64 + srow)*HID) + sseg;
    ACC_INIT;
    gemm_pipe(gA0, gA1, gB0, gB1, lA, lB, HID/32, tid, wrow, wcol, qsw, l16, acc);
#pragma unroll
    for (int mt = 0; mt < 4; mt++)
#pragma unroll
      for (int nt = 0; nt < 4; nt++)
#pragma unroll
        for (int r = 0; r < 4; r++){
          int m = bm + wrow + mt*16 + quad*4 + r;
          int n = bn + wcol + nt*16 + l16;
          float v = acc[mt][nt][r]; v = fmaxf(v, 0.f); v *= v;
          shh[(size_t)m*SI + n] = f2bf(v);
        }
  } else {
    // expert up: hws[slot][512] = bf16(relu2(x_t . up_e^T) * w)
    int eu = blk - 256;
    int pv = plan[1 + (eu >> 2)];
    if (pv < 0) return;
    int e = pv & 255;
    int tb = pv >> 8;
    int c = cnt[e];
    int bn = (eu & 3) * 128;
    const int* tl = tok + e * T_TOK;
    const float* wle = wl + e * T_TOK;
    int s0 = tb + srow;      if (s0 > c-1) s0 = c-1;
    int s1 = tb + 64 + srow; if (s1 > c-1) s1 = c-1;
    int t0 = tl[s0] >> 3, t1 = tl[s1] >> 3;
    const char* gA0 = (const char*)(xb + (size_t)t0*HID) + sseg;
    const char* gA1 = (const char*)(xb + (size_t)t1*HID) + sseg;
    const u16* Bb = upb + (size_t)e * IM * HID;
    const char* gB0 = (const char*)(Bb + (size_t)(bn + srow)*HID) + sseg;
    const char* gB1 = (const char*)(Bb + (size_t)(bn + 64 + srow)*HID) + sseg;
    ACC_INIT;
    gemm_pipe(gA0, gA1, gB0, gB1, lA, lB, HID/32, tid, wrow, wcol, qsw, l16, acc);
#pragma unroll
    for (int mt = 0; mt < 4; mt++)
#pragma unroll
      for (int r = 0; r < 4; r++){
        int s = tb + wrow + mt*16 + quad*4 + r;
        if (s < c){
          int code = tl[s];
          float w = wle[s];
          size_t hb = ((size_t)(code >> 3) * TOPK + (code & 7)) * IM;
#pragma unroll
          for (int nt = 0; nt < 4; nt++){
            float v = acc[mt][nt][r]; v = fmaxf(v, 0.f); v = v * v * w;
            hws[hb + bn + wcol + nt*16 + l16] = f2bf(v);
          }
        }
      }
  }
}

// K4: logical blocks [0,128) shared-down (64 K-iters, early dispatch),
// [128,1408) expert-down (16 K-iters). XCD swizzle (1408 = 8*176).
// out pre-zeroed; all writers atomic.
__global__ __launch_bounds__(256) void down_fused_kernel(
    const u16* __restrict__ shh, const u16* __restrict__ sdnb,
    const u16* __restrict__ hws, const u16* __restrict__ dnb,
    const int* __restrict__ cnt, const int* __restrict__ tok, const int* __restrict__ plan,
    float* __restrict__ out){
  __shared__ u16 lA[3*4096], lB[3*4096];
  GEO_INIT;
  int h = blockIdx.x;
  int blk = (h % 176) * 8 + h / 176;
  if (blk < 128){
    // shared down: out += H[2048][2048] . sdnW[1024][2048]^T
    int bm = (blk >> 3)*128, bn = (blk & 7)*128;
    const char* gA0 = (const char*)(shh + (size_t)(bm + srow)*SI) + sseg;
    const char* gA1 = (const char*)(shh + (size_t)(bm + 64 + srow)*SI) + sseg;
    const char* gB0 = (const char*)(sdnb + (size_t)(bn + srow)*SI) + sseg;
    const char* gB1 = (const char*)(sdnb + (size_t)(bn + 64 + srow)*SI) + sseg;
    ACC_INIT;
    gemm_pipe(gA0, gA1, gB0, gB1, lA, lB, SI/32, tid, wrow, wcol, qsw, l16, acc);
#pragma unroll
    for (int mt = 0; mt < 4; mt++)
#pragma unroll
      for (int nt = 0; nt < 4; nt++)
#pragma unroll
        for (int r = 0; r < 4; r++){
          int m = bm + wrow + mt*16 + quad*4 + r;
          int n = bn + wcol + nt*16 + l16;
          unsafeAtomicAdd(&out[(size_t)m*HID + n], acc[mt][nt][r]);
        }
  } else {
    // expert down: out[t] += h_slot . down_e^T
    int eu = blk - 128;
    int pv = plan[1 + (eu >> 3)];
    if (pv < 0) return;
    int e = pv & 255;
    int tb = pv >> 8;
    int c = cnt[e];
    int bn = (eu & 7) * 128;
    const int* tl = tok + e * T_TOK;
    int s0 = tb + srow;      if (s0 > c-1) s0 = c-1;
    int s1 = tb + 64 + srow; if (s1 > c-1) s1 = c-1;
    int c0 = tl[s0], c1 = tl[s1];
    const char* gA0 = (const char*)(hws + ((size_t)(c0 >> 3)*TOPK + (c0 & 7))*IM) + sseg;
    const char* gA1 = (const char*)(hws + ((size_t)(c1 >> 3)*TOPK + (c1 & 7))*IM) + sseg;
    const u16* Bb = dnb + (size_t)e * HID * IM;
    const char* gB0 = (const char*)(Bb + (size_t)(bn + srow)*IM) + sseg;
    const char* gB1 = (const char*)(Bb + (size_t)(bn + 64 + srow)*IM) + sseg;
    ACC_INIT;
    gemm_pipe(gA0, gA1, gB0, gB1, lA, lB, IM/32, tid, wrow, wcol, qsw, l16, acc);
#pragma unroll
    for (int mt = 0; mt < 4; mt++)
#pragma unroll
      for (int r = 0; r < 4; r++){
        int s = tb + wrow + mt*16 + quad*4 + r;
        if (s < c){
          int code = tl[s];
          float* ob = out + (size_t)(code >> 3) * HID;
#pragma unroll
          for (int nt = 0; nt < 4; nt++)
            unsafeAtomicAdd(&ob[bn + wcol + nt*16 + l16], acc[mt][nt][r]);
        }
      }
  }
}

extern "C" void kernel_launch(void* const* d_in, const int* in_sizes, int n_in,
                              void* d_out, int out_size, void* d_ws, size_t ws_size,
                              hipStream_t stream) {
  const float* x    = (const float*)d_in[0];
  const float* gate = (const float*)d_in[1];
  const float* eb   = (const float*)d_in[2];
  const float* upw  = (const float*)d_in[3];
  const float* dnw  = (const float*)d_in[4];
  const float* supw = (const float*)d_in[5];
  const float* sdnw = (const float*)d_in[6];
  float* out = (float*)d_out;

  char* w = (char*)d_ws;
  size_t o = 0;
  int*   cnt  = (int*)(w + o);   o += 1024;
  int*   plan = (int*)(w + o);   o += 1024;
  int*   ce   = (int*)(w + o);   o += (size_t)T_TOK * TOPK * 4;
  float* cw   = (float*)(w + o); o += (size_t)T_TOK * TOPK * 4;
  int*   tok  = (int*)(w + o);   o += (size_t)NEXP * T_TOK * 4;
  float* wl   = (float*)(w + o); o += (size_t)NEXP * T_TOK * 4;
  u16*   xb   = (u16*)(w + o);   o += (size_t)T_TOK * HID * 2;
  u16*   dnb  = (u16*)(w + o);   o += (size_t)NEXP * HID * IM * 2;
  u16*   hws  = (u16*)(w + o);   o += (size_t)T_TOK * TOPK * IM * 2;
  u16*   upb  = (u16*)(w + o);   o += (size_t)NEXP * IM * HID * 2;
  u16*   supb = (u16*)(w + o);   o += (size_t)SI * HID * 2;
  u16*   sdnb = (u16*)(w + o);   o += (size_t)HID * SI * 2;
  u16*   shh  = (u16*)(w + o);   o += (size_t)T_TOK * SI * 2;
  int*   done = cnt + 32;        // lives in cnt's padding

  (void)hipMemsetAsync(out, 0, (size_t)T_TOK * HID * 4, stream);
  prep_kernel<<<10240, 256, 0, stream>>>(
      x, upw, dnw, supw, sdnw, gate, eb,
      (u16x8*)xb, (u16x8*)upb, (u16x8*)dnb, (u16x8*)supb, (u16x8*)sdnb,
      ce, cw, done);
  build_plan_kernel<<<NEXP, 256, 0, stream>>>(ce, cw, cnt, tok, wl, done, plan);
  up_fused_kernel<<<896, 256, 0, stream>>>(xb, supb, upb, cnt, tok, wl, plan, shh, hws);
  down_fused_kernel<<<1408, 256, 0, stream>>>(shh, sdnb, hws, dnb, cnt, tok, plan, out);
}

// Round 11
// 335.622 us; speedup vs baseline: 1.1795x; 1.1597x over previous
//
#include <hip/hip_runtime.h>

typedef unsigned short u16;
typedef __bf16 bf16x8 __attribute__((ext_vector_type(8)));
typedef float f32x4 __attribute__((ext_vector_type(4)));
typedef u16 u16x8 __attribute__((ext_vector_type(8)));

#define T_TOK 2048
#define HID   1024
#define NEXP  32
#define IM    512
#define SI    2048
#define TOPK  6
#define PLAN_MAX 160

// exact RNE float->bf16
__device__ __forceinline__ u16 f2bf(float f){
  unsigned u = __float_as_uint(f);
  u += 0x7FFFu + ((u >> 16) & 1u);
  return (u16)(u >> 16);
}

__device__ __forceinline__ ushort4 cvt4(float4 a){
  ushort4 o; o.x = f2bf(a.x); o.y = f2bf(a.y); o.z = f2bf(a.z); o.w = f2bf(a.w);
  return o;
}

// async global->LDS, 16B per lane. LDS dest must be wave-uniform base + lane*16.
__device__ __forceinline__ void gll16(const void* g, void* l){
  __builtin_amdgcn_global_load_lds((const __attribute__((address_space(1))) void*)g,
                                   (__attribute__((address_space(3))) void*)l, 16, 0, 0);
}

// K1: router (blocks 0..511) + cvt of ALL fp32->bf16 regions (512..19967).
// cvt uses an LDS bounce so BOTH global streams are full-width coalesced:
// loads 16B/lane contiguous, stores 16B/lane contiguous. LDS: write ushort4
// @8B stride (2-way, free), read b128 @16B stride (2-way per phase, free).
// ONE u16x8 output slot per thread. Region slot counts (u16x8 = 8 floats):
//   x 262144 | upw 2097152 | dnw 2097152 | supw 262144 | sdnw 262144
//   total 4980736 = 19456 blocks x 256. All boundaries multiples of 256.
__global__ __launch_bounds__(256) void prep_kernel(
    const float* __restrict__ x, const float* __restrict__ upw, const float* __restrict__ dnw,
    const float* __restrict__ supw, const float* __restrict__ sdnw,
    const float* __restrict__ gate, const float* __restrict__ ebias,
    u16x8* __restrict__ xb, u16x8* __restrict__ upb, u16x8* __restrict__ dnb,
    u16x8* __restrict__ supb, u16x8* __restrict__ sdnb,
    int* __restrict__ ce, float* __restrict__ cw, int* __restrict__ done){
  int blk = blockIdx.x;
  if (blk == 0 && threadIdx.x == 0) *done = 0;
  if (blk >= 512){
    __shared__ __align__(16) ushort4 lds[512];
    long ob = (long)(blk - 512) * 256;      // global output slot base of block
    const float4* s; u16x8* d; long rb;
    if      (ob <  262144L){ s = (const float4*)x;    d = xb;   rb = ob; }
    else if (ob < 2359296L){ s = (const float4*)upw;  d = upb;  rb = ob -  262144L; }
    else if (ob < 4456448L){ s = (const float4*)dnw;  d = dnb;  rb = ob - 2359296L; }
    else if (ob < 4718592L){ s = (const float4*)supw; d = supb; rb = ob - 4456448L; }
    else                   { s = (const float4*)sdnw; d = sdnb; rb = ob - 4718592L; }
    int tid = threadIdx.x;
    float4 a = s[2*rb + tid];               // 16B/lane, block covers 512 float4
    float4 b = s[2*rb + 256 + tid];
    lds[tid]       = cvt4(a);               // lds[j] = cvt(s[2*rb + j])
    lds[tid + 256] = cvt4(b);
    __syncthreads();
    d[rb + tid] = *(const u16x8*)&lds[2*tid];   // 16B/lane store
    return;
  }
  // ---- router: 4 tokens/block, 1 wave/token, register cross-lane top-k ----
  int wave = threadIdx.x >> 6;
  int lane = threadIdx.x & 63;
  int t = blk * 4 + wave;
  int e = lane & 31, half = lane >> 5;
  const float4* xv = (const float4*)(x + (size_t)t * HID);
  const float4* gv = (const float4*)(gate + (size_t)e * HID);
  double d0a = 0, d1a = 0, d2a = 0, d3a = 0;
  for (int i = half * 128; i < half * 128 + 128; i++){
    float4 a = xv[i], b = gv[i];
    d0a += (double)a.x * b.x; d1a += (double)a.y * b.y;
    d2a += (double)a.z * b.z; d3a += (double)a.w * b.w;
  }
  double acc = (d0a + d1a) + (d2a + d3a);
  acc += __shfl_xor(acc, 32);
  double score = 1.0 / (1.0 + exp(-acc));
  double sc = score + (double)ebias[e];
  double o1  = __shfl_xor(sc, 1);
  double hi  = fmax(sc, o1), lo = fmin(sc, o1);
  double ohi = __shfl_xor(hi, 2), olo = __shfl_xor(lo, 2);
  double gs  = (hi >= ohi) ? hi + fmax(lo, ohi) : ohi + fmax(olo, hi);
  int g = e >> 2;
  int rank = 0;
#pragma unroll
  for (int j = 0; j < 8; j++){
    double gj = __shfl(gs, j * 4);
    if (gj > gs || (gj == gs && j < g)) rank++;
  }
  double cur = (rank < 4) ? sc : 0.0;
  int sel_e[TOPK]; double sel_w[TOPK]; double wsum = 0.0;
#pragma unroll
  for (int k = 0; k < TOPK; k++){
    double bv = cur; int bi = lane;
#pragma unroll
    for (int m = 32; m >= 1; m >>= 1){
      double ov = __shfl_xor(bv, m); int oi = __shfl_xor(bi, m);
      if (ov > bv || (ov == bv && oi < bi)) { bv = ov; bi = oi; }
    }
    if ((bi & 31) == e) cur = -1e300;
    double ws = __shfl(score, bi);
    sel_e[k] = bi; sel_w[k] = ws; wsum += ws;
  }
  double scale = 2.5 / (wsum + 1e-20);
#pragma unroll
  for (int k = 0; k < TOPK; k++){
    if (lane == k){                       // compile-time idx -> no scratch spill
      ce[t * TOPK + k] = sel_e[k] & 31;
      cw[t * TOPK + k] = (float)(sel_w[k] * scale);
    }
  }
}

// 32 blocks (one per expert): ordered compaction via ballot prefix scan.
// Last-arriving block builds the dense tile plan.
__global__ __launch_bounds__(256) void build_plan_kernel(const int* __restrict__ ce,
                                                         const float* __restrict__ cw,
                                                         int* __restrict__ cnt,
                                                         int* __restrict__ tok,
                                                         float* __restrict__ wl,
                                                         int* __restrict__ done,
                                                         int* __restrict__ plan){
  int e = blockIdx.x;
  int tid = threadIdx.x, lane = tid & 63, wave = tid >> 6;
  __shared__ int wsum[4];
  __shared__ int lastflag;
  int running = 0;
  for (int base = 0; base < T_TOK * TOPK; base += 256){
    int i = base + tid;                       // 12288 = 48*256, no bounds check
    bool m = (ce[i] == e);
    unsigned long long bal = __ballot(m);
    int woff = __popcll(bal & ((1ull << lane) - 1ull));
    if (lane == 0) wsum[wave] = __popcll(bal);
    __syncthreads();
    int wbase = 0;
#pragma unroll
    for (int wv = 0; wv < 4; wv++) if (wv < wave) wbase += wsum[wv];
    int btot = wsum[0] + wsum[1] + wsum[2] + wsum[3];
    if (m){
      int t = i / TOPK, k = i - t * TOPK;
      int pos = running + wbase + woff;
      tok[e * T_TOK + pos] = (t << 3) | k;
      wl[e * T_TOK + pos] = cw[i];
    }
    running += btot;
    __syncthreads();                          // wsum WAR hazard for next iter
  }
  if (tid == 0){
    atomicExch(&cnt[e], running);             // write-through, device-visible
    __threadfence();
    lastflag = (atomicAdd(done, 1) == NEXP - 1);
  }
  __syncthreads();
  if (lastflag){
    __threadfence();                          // acquire: other blocks' cnt visible
    if (tid < PLAN_MAX) plan[1 + tid] = -1;
    __syncthreads();
    if (tid == 0){
      int n = 0;
      for (int ee = 0; ee < NEXP; ee++){
        int c = (ee == e) ? running : cnt[ee];
        for (int tb = 0; tb < c; tb += 128) plan[1 + n++] = (tb << 8) | ee;
      }
      plan[0] = n;
    }
  }
}

// ---- 128x128 tile, BK=32, 3-buffer pipeline with COUNTED vmcnt (round-5 core,
// verified 335.7us): loads for the next 2 K-tiles stay in flight ACROSS the
// barriers (never drain to 0 in the main loop) -> ~2-iter latency tolerance.
// Source 16B-segment swizzle keeps ds_read_b128 conflict-free while the gll16
// LDS dest stays linear (rule #21).
__device__ __forceinline__ void gemm_pipe(
    const char* gA0, const char* gA1, const char* gB0, const char* gB1,
    u16* lA, u16* lB, int iters, int tid, int wrow, int wcol, int qsw, int l16,
    f32x4 acc[4][4])
{
  char* bA = (char*)lA + tid*16;
  char* bB = (char*)lB + tid*16;
#define STAGE(t, b) do { \
    gll16(gA0 + (size_t)(t)*64, bA + (size_t)(b)*8192); \
    gll16(gA1 + (size_t)(t)*64, bA + (size_t)(b)*8192 + 4096); \
    gll16(gB0 + (size_t)(t)*64, bB + (size_t)(b)*8192); \
    gll16(gB1 + (size_t)(t)*64, bB + (size_t)(b)*8192 + 4096); } while(0)
#define COMPUTE(rbuf) do { \
    const u16* rA = lA + (rbuf)*4096; \
    const u16* rB = lB + (rbuf)*4096; \
    bf16x8 af[4], bfr[4]; \
    _Pragma("unroll") \
    for (int mt = 0; mt < 4; mt++) af[mt]  = *(const bf16x8*)&rA[(wrow + mt*16 + l16)*32 + qsw*8]; \
    _Pragma("unroll") \
    for (int nt = 0; nt < 4; nt++) bfr[nt] = *(const bf16x8*)&rB[(wcol + nt*16 + l16)*32 + qsw*8]; \
    _Pragma("unroll") \
    for (int mt = 0; mt < 4; mt++) \
    _Pragma("unroll") \
      for (int nt = 0; nt < 4; nt++) \
        acc[mt][nt] = __builtin_amdgcn_mfma_f32_16x16x32_bf16(af[mt], bfr[nt], acc[mt][nt], 0, 0, 0); \
    } while(0)

  STAGE(0, 0); STAGE(1, 1);
  int rb = 0, sb = 2;
  for (int it = 0; it < iters - 2; ++it){
    STAGE(it + 2, sb);
    asm volatile("s_waitcnt vmcnt(8)" ::: "memory");   // own T(it) landed; T(it+1),T(it+2) in flight
    __builtin_amdgcn_s_barrier();                      // all waves' T(it) landed
    asm volatile("" ::: "memory");
    COMPUTE(rb);
    asm volatile("" ::: "memory");
    __builtin_amdgcn_s_barrier();                      // reads of buf rb done -> may be restaged
    asm volatile("" ::: "memory");
    rb = (rb + 1 == 3) ? 0 : rb + 1;
    sb = (sb + 1 == 3) ? 0 : sb + 1;
  }
  asm volatile("s_waitcnt vmcnt(4)" ::: "memory");
  __builtin_amdgcn_s_barrier();
  asm volatile("" ::: "memory");
  COMPUTE(rb);
  asm volatile("" ::: "memory");
  __builtin_amdgcn_s_barrier();
  asm volatile("" ::: "memory");
  rb = (rb + 1 == 3) ? 0 : rb + 1;
  asm volatile("s_waitcnt vmcnt(0)" ::: "memory");
  __builtin_amdgcn_s_barrier();
  asm volatile("" ::: "memory");
  COMPUTE(rb);
#undef STAGE
#undef COMPUTE
}

#define ACC_INIT f32x4 acc[4][4]; \
  _Pragma("unroll") for (int i_ = 0; i_ < 4; i_++) \
  _Pragma("unroll") for (int j_ = 0; j_ < 4; j_++) acc[i_][j_] = (f32x4){0.f,0.f,0.f,0.f};

#define GEO_INIT int tid = threadIdx.x; \
  int lane = tid & 63, wave = tid >> 6, quad = lane >> 4, l16 = lane & 15; \
  int wrow = (wave >> 1)*64, wcol = (wave & 1)*64; \
  int srow = tid >> 2; \
  int sseg = ((tid & 3) ^ ((tid >> 3) & 3)) * 16; \
  int qsw  = quad ^ ((l16 >> 1) & 3);

// K3: blocks [0,256) shared-up, [256,896) expert-up. All 32 K-iters.
__global__ __launch_bounds__(256) void up_fused_kernel(
    const u16* __restrict__ xb, const u16* __restrict__ supb, const u16* __restrict__ upb,
    const int* __restrict__ cnt, const int* __restrict__ tok, const float* __restrict__ wl,
    const int* __restrict__ plan, u16* __restrict__ shh, u16* __restrict__ hws){
  __shared__ u16 lA[3*4096], lB[3*4096];
  GEO_INIT;
  int blk = blockIdx.x;
  if (blk < 256){
    // shared up: shh[2048][2048] = bf16(relu2(X . supW^T))
    int bm = (blk >> 4) * 128, bn = (blk & 15) * 128;
    const char* gA0 = (const char*)(xb + (size_t)(bm + srow)*HID) + sseg;
    const char* gA1 = (const char*)(xb + (size_t)(bm + 64 + srow)*HID) + sseg;
    const char* gB0 = (const char*)(supb + (size_t)(bn + srow)*HID) + sseg;
    const char* gB1 = (const char*)(supb + (size_t)(bn + 64 + srow)*HID) + sseg;
    ACC_INIT;
    gemm_pipe(gA0, gA1, gB0, gB1, lA, lB, HID/32, tid, wrow, wcol, qsw, l16, acc);
#pragma unroll
    for (int mt = 0; mt < 4; mt++)
#pragma unroll
      for (int nt = 0; nt < 4; nt++)
#pragma unroll
        for (int r = 0; r < 4; r++){
          int m = bm + wrow + mt*16 + quad*4 + r;
          int n = bn + wcol + nt*16 + l16;
          float v = acc[mt][nt][r]; v = fmaxf(v, 0.f); v *= v;
          shh[(size_t)m*SI + n] = f2bf(v);
        }
  } else {
    // expert up: hws[slot][512] = bf16(relu2(x_t . up_e^T) * w)
    int eu = blk - 256;
    int pv = plan[1 + (eu >> 2)];
    if (pv < 0) return;
    int e = pv & 255;
    int tb = pv >> 8;
    int c = cnt[e];
    int bn = (eu & 3) * 128;
    const int* tl = tok + e * T_TOK;
    const float* wle = wl + e * T_TOK;
    int s0 = tb + srow;      if (s0 > c-1) s0 = c-1;
    int s1 = tb + 64 + srow; if (s1 > c-1) s1 = c-1;
    int t0 = tl[s0] >> 3, t1 = tl[s1] >> 3;
    const char* gA0 = (const char*)(xb + (size_t)t0*HID) + sseg;
    const char* gA1 = (const char*)(xb + (size_t)t1*HID) + sseg;
    const u16* Bb = upb + (size_t)e * IM * HID;
    const char* gB0 = (const char*)(Bb + (size_t)(bn + srow)*HID) + sseg;
    const char* gB1 = (const char*)(Bb + (size_t)(bn + 64 + srow)*HID) + sseg;
    ACC_INIT;
    gemm_pipe(gA0, gA1, gB0, gB1, lA, lB, HID/32, tid, wrow, wcol, qsw, l16, acc);
#pragma unroll
    for (int mt = 0; mt < 4; mt++)
#pragma unroll
      for (int r = 0; r < 4; r++){
        int s = tb + wrow + mt*16 + quad*4 + r;
        if (s < c){
          int code = tl[s];
          float w = wle[s];
          size_t hb = ((size_t)(code >> 3) * TOPK + (code & 7)) * IM;
#pragma unroll
          for (int nt = 0; nt < 4; nt++){
            float v = acc[mt][nt][r]; v = fmaxf(v, 0.f); v = v * v * w;
            hws[hb + bn + wcol + nt*16 + l16] = f2bf(v);
          }
        }
      }
  }
}

// K4: blocks [0,128) shared-down (64 K-iters, dispatched first),
// [128,1408) expert-down (16 K-iters). out pre-zeroed; all writers atomic.
__global__ __launch_bounds__(256) void down_fused_kernel(
    const u16* __restrict__ shh, const u16* __restrict__ sdnb,
    const u16* __restrict__ hws, const u16* __restrict__ dnb,
    const int* __restrict__ cnt, const int* __restrict__ tok, const int* __restrict__ plan,
    float* __restrict__ out){
  __shared__ u16 lA[3*4096], lB[3*4096];
  GEO_INIT;
  int blk = blockIdx.x;
  if (blk < 128){
    // shared down: out += H[2048][2048] . sdnW[1024][2048]^T
    int bm = (blk >> 3)*128, bn = (blk & 7)*128;
    const char* gA0 = (const char*)(shh + (size_t)(bm + srow)*SI) + sseg;
    const char* gA1 = (const char*)(shh + (size_t)(bm + 64 + srow)*SI) + sseg;
    const char* gB0 = (const char*)(sdnb + (size_t)(bn + srow)*SI) + sseg;
    const char* gB1 = (const char*)(sdnb + (size_t)(bn + 64 + srow)*SI) + sseg;
    ACC_INIT;
    gemm_pipe(gA0, gA1, gB0, gB1, lA, lB, SI/32, tid, wrow, wcol, qsw, l16, acc);
#pragma unroll
    for (int mt = 0; mt < 4; mt++)
#pragma unroll
      for (int nt = 0; nt < 4; nt++)
#pragma unroll
        for (int r = 0; r < 4; r++){
          int m = bm + wrow + mt*16 + quad*4 + r;
          int n = bn + wcol + nt*16 + l16;
          unsafeAtomicAdd(&out[(size_t)m*HID + n], acc[mt][nt][r]);
        }
  } else {
    // expert down: out[t] += h_slot . down_e^T
    int eu = blk - 128;
    int pv = plan[1 + (eu >> 3)];
    if (pv < 0) return;
    int e = pv & 255;
    int tb = pv >> 8;
    int c = cnt[e];
    int bn = (eu & 7) * 128;
    const int* tl = tok + e * T_TOK;
    int s0 = tb + srow;      if (s0 > c-1) s0 = c-1;
    int s1 = tb + 64 + srow; if (s1 > c-1) s1 = c-1;
    int c0 = tl[s0], c1 = tl[s1];
    const char* gA0 = (const char*)(hws + ((size_t)(c0 >> 3)*TOPK + (c0 & 7))*IM) + sseg;
    const char* gA1 = (const char*)(hws + ((size_t)(c1 >> 3)*TOPK + (c1 & 7))*IM) + sseg;
    const u16* Bb = dnb + (size_t)e * HID * IM;
    const char* gB0 = (const char*)(Bb + (size_t)(bn + srow)*IM) + sseg;
    const char* gB1 = (const char*)(Bb + (size_t)(bn + 64 + srow)*IM) + sseg;
    ACC_INIT;
    gemm_pipe(gA0, gA1, gB0, gB1, lA, lB, IM/32, tid, wrow, wcol, qsw, l16, acc);
#pragma unroll
    for (int mt = 0; mt < 4; mt++)
#pragma unroll
      for (int r = 0; r < 4; r++){
        int s = tb + wrow + mt*16 + quad*4 + r;
        if (s < c){
          int code = tl[s];
          float* ob = out + (size_t)(code >> 3) * HID;
#pragma unroll
          for (int nt = 0; nt < 4; nt++)
            unsafeAtomicAdd(&ob[bn + wcol + nt*16 + l16], acc[mt][nt][r]);
        }
      }
  }
}

extern "C" void kernel_launch(void* const* d_in, const int* in_sizes, int n_in,
                              void* d_out, int out_size, void* d_ws, size_t ws_size,
                              hipStream_t stream) {
  const float* x    = (const float*)d_in[0];
  const float* gate = (const float*)d_in[1];
  const float* eb   = (const float*)d_in[2];
  const float* upw  = (const float*)d_in[3];
  const float* dnw  = (const float*)d_in[4];
  const float* supw = (const float*)d_in[5];
  const float* sdnw = (const float*)d_in[6];
  float* out = (float*)d_out;

  char* w = (char*)d_ws;
  size_t o = 0;
  int*   cnt  = (int*)(w + o);   o += 1024;
  int*   plan = (int*)(w + o);   o += 1024;
  int*   ce   = (int*)(w + o);   o += (size_t)T_TOK * TOPK * 4;
  float* cw   = (float*)(w + o); o += (size_t)T_TOK * TOPK * 4;
  int*   tok  = (int*)(w + o);   o += (size_t)NEXP * T_TOK * 4;
  float* wl   = (float*)(w + o); o += (size_t)NEXP * T_TOK * 4;
  u16*   xb   = (u16*)(w + o);   o += (size_t)T_TOK * HID * 2;
  u16*   dnb  = (u16*)(w + o);   o += (size_t)NEXP * HID * IM * 2;
  u16*   hws  = (u16*)(w + o);   o += (size_t)T_TOK * TOPK * IM * 2;
  u16*   upb  = (u16*)(w + o);   o += (size_t)NEXP * IM * HID * 2;
  u16*   supb = (u16*)(w + o);   o += (size_t)SI * HID * 2;
  u16*   sdnb = (u16*)(w + o);   o += (size_t)HID * SI * 2;
  u16*   shh  = (u16*)(w + o);   o += (size_t)T_TOK * SI * 2;
  int*   done = cnt + 32;        // lives in cnt's padding

  (void)hipMemsetAsync(out, 0, (size_t)T_TOK * HID * 4, stream);
  prep_kernel<<<19968, 256, 0, stream>>>(
      x, upw, dnw, supw, sdnw, gate, eb,
      (u16x8*)xb, (u16x8*)upb, (u16x8*)dnb, (u16x8*)supb, (u16x8*)sdnb,
      ce, cw, done);
  build_plan_kernel<<<NEXP, 256, 0, stream>>>(ce, cw, cnt, tok, wl, done, plan);
  up_fused_kernel<<<896, 256, 0, stream>>>(xb, supb, upb, cnt, tok, wl, plan, shh, hws);
  down_fused_kernel<<<1408, 256, 0, stream>>>(shh, sdnb, hws, dnb, cnt, tok, plan, out);
}